// Round 5
// baseline (88.773 us; speedup 1.0000x reference)
//
#include <hip/hip_runtime.h>
#include <hip/hip_bf16.h>

typedef __attribute__((ext_vector_type(8))) short short8;
typedef __attribute__((ext_vector_type(4))) float f32x4;

#define MAXNBR 128
#define ALPHA 0.2f

static __device__ __forceinline__ unsigned short f2bf(float f) {
    union { float f; unsigned u; } v; v.f = f;
    unsigned r = v.u + 0x7FFF + ((v.u >> 16) & 1);
    return (unsigned short)(r >> 16);
}
static __device__ __forceinline__ float bf2f(unsigned short u) {
    union { unsigned u; float f; } v; v.u = ((unsigned)u) << 16;
    return v.f;
}

// ---------- K0: cvt x -> bf16, W1 -> W1t bf16 ----------
__global__ __launch_bounds__(256) void cvt(const float* __restrict__ x,
                                           unsigned short* __restrict__ xb,
                                           const float* __restrict__ W1,
                                           unsigned short* __restrict__ W1t) {
    int b = blockIdx.x, t = threadIdx.x;
    if (b < 1024) {                       // x: 8 elems/thread
        size_t base = (size_t)b * 2048 + t * 8;
        float4 v0 = *(const float4*)&x[base];
        float4 v1 = *(const float4*)&x[base + 4];
        short8 o;
        o[0] = f2bf(v0.x); o[1] = f2bf(v0.y); o[2] = f2bf(v0.z); o[3] = f2bf(v0.w);
        o[4] = f2bf(v1.x); o[5] = f2bf(v1.y); o[6] = f2bf(v1.z); o[7] = f2bf(v1.w);
        *(short8*)&xb[base] = o;
    } else {                              // W1t transpose: 1 elem/thread
        int idx = (b - 1024) * 256 + t;   // out index c*512+k
        int c = idx >> 9, k = idx & 511;
        W1t[idx] = f2bf(W1[(size_t)k * 1024 + c]);
    }
}

// ---------- K1: fused GEMM (512 blocks) + adjacency scan (1024 blocks) ----------
__global__ __launch_bounds__(256) void gemm_scan(const unsigned short* __restrict__ A,
                                                 const unsigned short* __restrict__ Bt,
                                                 unsigned short* __restrict__ C,
                                                 const float* __restrict__ adj,
                                                 int* __restrict__ nbr_idx,
                                                 int* __restrict__ nbr_cnt) {
    __shared__ unsigned short Asm[128 * 64];   // 16 KB
    __shared__ unsigned short Bsm[64 * 64];    //  8 KB
    int b = blockIdx.x;
    int tid = threadIdx.x;
    if (b < 512) {
        // ----- GEMM: h1b[4096][1024] = xb[4096][512] @ W1t; BM=128 BN=64 -----
        int lane = tid & 63;
        int w = tid >> 6;
        int wr = w >> 1, wc = w & 1;           // waves 2x2; wave tile 64x32
        int rowBase = (b & 31) * 128, colBase = (b >> 5) * 64;
        int lr = lane >> 3;
        int lc = (lane & 7) * 8;
        f32x4 acc[4][2] = {};
        for (int k0 = 0; k0 < 512; k0 += 64) {
            #pragma unroll
            for (int i = 0; i < 4; ++i) {
                int rA = i * 32 + w * 8;
                __builtin_amdgcn_global_load_lds(
                    (const __attribute__((address_space(1))) void*)&A[(size_t)(rowBase + rA + lr) * 512 + k0 + lc],
                    (__attribute__((address_space(3))) void*)&Asm[rA * 64],
                    16, 0, 0);
            }
            #pragma unroll
            for (int i = 0; i < 2; ++i) {
                int rB = i * 32 + w * 8;
                __builtin_amdgcn_global_load_lds(
                    (const __attribute__((address_space(1))) void*)&Bt[(size_t)(colBase + rB + lr) * 512 + k0 + lc],
                    (__attribute__((address_space(3))) void*)&Bsm[rB * 64],
                    16, 0, 0);
            }
            __syncthreads();
            #pragma unroll
            for (int kk = 0; kk < 64; kk += 32) {
                short8 af[4], bfv[2];
                int kf = kk + (lane >> 4) * 8;
                #pragma unroll
                for (int m = 0; m < 4; ++m)
                    af[m] = *(const short8*)&Asm[(wr * 64 + m * 16 + (lane & 15)) * 64 + kf];
                #pragma unroll
                for (int n = 0; n < 2; ++n)
                    bfv[n] = *(const short8*)&Bsm[(wc * 32 + n * 16 + (lane & 15)) * 64 + kf];
                #pragma unroll
                for (int m = 0; m < 4; ++m)
                    #pragma unroll
                    for (int n = 0; n < 2; ++n)
                        acc[m][n] = __builtin_amdgcn_mfma_f32_16x16x32_bf16(af[m], bfv[n], acc[m][n], 0, 0, 0);
            }
            __syncthreads();
        }
        int crow0 = rowBase + wr * 64, ccol0 = colBase + wc * 32;
        #pragma unroll
        for (int m = 0; m < 4; ++m)
            #pragma unroll
            for (int n = 0; n < 2; ++n) {
                int col = ccol0 + n * 16 + (lane & 15);
                int row0 = crow0 + m * 16 + (lane >> 4) * 4;
                #pragma unroll
                for (int r = 0; r < 4; ++r)
                    C[(size_t)(row0 + r) * 1024 + col] = f2bf(acc[m][n][r]);
            }
    } else {
        // ----- adjacency scan: 4 rows/block, one wave each -----
        int row = (b - 512) * 4 + (tid >> 6);
        int lane = tid & 63;
        const float* arow = adj + (size_t)row * 4096;
        int cnt = 0;
        for (int base = 0; base < 4096; base += 256) {
            float4 v = *(const float4*)&arow[base + lane * 4];
            #pragma unroll
            for (int s = 0; s < 4; ++s) {
                float xv = ((const float*)&v)[s];
                unsigned long long m = __ballot(xv > 0.f);
                if (xv > 0.f) {
                    int pos = cnt + (int)__popcll(m & ((1ull << lane) - 1ull));
                    if (pos < MAXNBR) nbr_idx[row * MAXNBR + pos] = base + lane * 4 + s;
                }
                cnt += (int)__popcll(m);
            }
        }
        if (lane == 0) nbr_cnt[row] = cnt < MAXNBR ? cnt : MAXNBR;
    }
}

// ---------- K2: f_src1/f_dst1 [8][4096] from bf16 h1 ----------
__global__ __launch_bounds__(256) void attn_coef1(const unsigned short* __restrict__ h1b,
                                                  const float* __restrict__ a_src,
                                                  const float* __restrict__ a_dst,
                                                  float* __restrict__ f_src,
                                                  float* __restrict__ f_dst) {
    int n = blockIdx.x, t = threadIdx.x;
    ushort4 v = *(const ushort4*)&h1b[(size_t)n * 1024 + t * 4];
    int head = t >> 5;
    int o0 = (t * 4) & 127;
    float hv0 = bf2f(v.x), hv1 = bf2f(v.y), hv2 = bf2f(v.z), hv3 = bf2f(v.w);
    float ps = hv0 * a_src[head * 128 + o0] + hv1 * a_src[head * 128 + o0 + 1]
             + hv2 * a_src[head * 128 + o0 + 2] + hv3 * a_src[head * 128 + o0 + 3];
    float pd = hv0 * a_dst[head * 128 + o0] + hv1 * a_dst[head * 128 + o0 + 1]
             + hv2 * a_dst[head * 128 + o0 + 2] + hv3 * a_dst[head * 128 + o0 + 3];
    #pragma unroll
    for (int off = 1; off < 32; off <<= 1) {
        ps += __shfl_xor(ps, off);
        pd += __shfl_xor(pd, off);
    }
    if ((t & 31) == 0) {
        f_src[head * 4096 + n] = ps;
        f_dst[head * 4096 + n] = pd;
    }
}

// ---------- K3: XCD-affine feature-split aggregate: node i, quarter q (2 heads) ----------
// bid = i*4 + q  ->  XCD = bid%8 = q + 4*(i&1): each XCD touches only a 2 MB
// column stripe of h1b -> L2-resident gather. One wave per block.
__global__ __launch_bounds__(64) void aggregate2(const unsigned short* __restrict__ h1b,
                                                 const int* __restrict__ nbr_idx,
                                                 const int* __restrict__ nbr_cnt,
                                                 const float* __restrict__ f_src,
                                                 const float* __restrict__ f_dst,
                                                 const float* __restrict__ W2,
                                                 float* __restrict__ h2part) {
    __shared__ int nbr[MAXNBR];
    __shared__ float attw[2][MAXNBR];
    __shared__ float pored[64][17];
    int bid = blockIdx.x;
    int q = bid & 3;
    int i = bid >> 2;
    int t = threadIdx.x;
    int cnt = nbr_cnt[i];
    nbr[t]      = (t < cnt)      ? nbr_idx[i * MAXNBR + t]      : 0;
    nbr[t + 64] = (t + 64 < cnt) ? nbr_idx[i * MAXNBR + t + 64] : 0;
    __syncthreads();
    int hl = t >> 5;               // local head 0/1
    int h = q * 2 + hl;            // global head
    // ---- softmax for this block's 2 heads (lanes 0-31: head0, 32-63: head1) ----
    {
        int sl = t & 31;
        float fsh = f_src[h * 4096 + i];
        float e[4];
        #pragma unroll
        for (int p = 0; p < 4; ++p) {
            int j = sl + p * 32;
            if (j < cnt) {
                float xv = fsh + f_dst[h * 4096 + nbr[j]];
                e[p] = xv > 0.f ? xv : ALPHA * xv;
            } else e[p] = -INFINITY;
        }
        float m = fmaxf(fmaxf(e[0], e[1]), fmaxf(e[2], e[3]));
        #pragma unroll
        for (int off = 1; off < 32; off <<= 1) m = fmaxf(m, __shfl_xor(m, off));
        float wq[4];
        float s = 0.f;
        #pragma unroll
        for (int p = 0; p < 4; ++p) {
            wq[p] = (e[p] == -INFINITY) ? 0.f : __expf(e[p] - m);
            s += wq[p];
        }
        #pragma unroll
        for (int off = 1; off < 32; off <<= 1) s += __shfl_xor(s, off);
        float inv = 1.f / s;
        #pragma unroll
        for (int p = 0; p < 4; ++p) attw[hl][sl + p * 32] = wq[p] * inv;
    }
    __syncthreads();
    // ---- gather: lane t owns feats q*256 + t*4 .. +3 (head h = hl) ----
    const unsigned short* src = h1b + q * 256 + t * 4;
    float a0 = 0.f, a1 = 0.f, a2 = 0.f, a3 = 0.f;
    int cntPad = (cnt + 7) & ~7;
    for (int j = 0; j < cntPad; j += 8) {
        int4 nb0 = *(const int4*)&nbr[j];
        int4 nb1 = *(const int4*)&nbr[j + 4];
        float4 w0 = *(const float4*)&attw[hl][j];
        float4 w1 = *(const float4*)&attw[hl][j + 4];
        ushort4 v0 = *(const ushort4*)&src[(size_t)nb0.x << 10];
        ushort4 v1 = *(const ushort4*)&src[(size_t)nb0.y << 10];
        ushort4 v2 = *(const ushort4*)&src[(size_t)nb0.z << 10];
        ushort4 v3 = *(const ushort4*)&src[(size_t)nb0.w << 10];
        ushort4 v4 = *(const ushort4*)&src[(size_t)nb1.x << 10];
        ushort4 v5 = *(const ushort4*)&src[(size_t)nb1.y << 10];
        ushort4 v6 = *(const ushort4*)&src[(size_t)nb1.z << 10];
        ushort4 v7 = *(const ushort4*)&src[(size_t)nb1.w << 10];
        a0 += w0.x * bf2f(v0.x) + w0.y * bf2f(v1.x) + w0.z * bf2f(v2.x) + w0.w * bf2f(v3.x)
            + w1.x * bf2f(v4.x) + w1.y * bf2f(v5.x) + w1.z * bf2f(v6.x) + w1.w * bf2f(v7.x);
        a1 += w0.x * bf2f(v0.y) + w0.y * bf2f(v1.y) + w0.z * bf2f(v2.y) + w0.w * bf2f(v3.y)
            + w1.x * bf2f(v4.y) + w1.y * bf2f(v5.y) + w1.z * bf2f(v6.y) + w1.w * bf2f(v7.y);
        a2 += w0.x * bf2f(v0.z) + w0.y * bf2f(v1.z) + w0.z * bf2f(v2.z) + w0.w * bf2f(v3.z)
            + w1.x * bf2f(v4.z) + w1.y * bf2f(v5.z) + w1.z * bf2f(v6.z) + w1.w * bf2f(v7.z);
        a3 += w0.x * bf2f(v0.w) + w0.y * bf2f(v1.w) + w0.z * bf2f(v2.w) + w0.w * bf2f(v3.w)
            + w1.x * bf2f(v4.w) + w1.y * bf2f(v5.w) + w1.z * bf2f(v6.w) + w1.w * bf2f(v7.w);
    }
    a0 = a0 > 0.f ? a0 : expm1f(a0);
    a1 = a1 > 0.f ? a1 : expm1f(a1);
    a2 = a2 > 0.f ? a2 : expm1f(a2);
    a3 = a3 > 0.f ? a3 : expm1f(a3);
    // ---- layer-2 partial: po[o] = sum_{r=0..3} v_r * W2[q*256+t*4+r][o] ----
    float po[16];
    {
        int f0 = q * 256 + t * 4;
        float4 wr0 = *(const float4*)&W2[(size_t)(f0 + 0) * 16];
        float4 wr1 = *(const float4*)&W2[(size_t)(f0 + 0) * 16 + 4];
        float4 wr2 = *(const float4*)&W2[(size_t)(f0 + 0) * 16 + 8];
        float4 wr3 = *(const float4*)&W2[(size_t)(f0 + 0) * 16 + 12];
        po[0] = a0 * wr0.x; po[1] = a0 * wr0.y; po[2] = a0 * wr0.z; po[3] = a0 * wr0.w;
        po[4] = a0 * wr1.x; po[5] = a0 * wr1.y; po[6] = a0 * wr1.z; po[7] = a0 * wr1.w;
        po[8] = a0 * wr2.x; po[9] = a0 * wr2.y; po[10] = a0 * wr2.z; po[11] = a0 * wr2.w;
        po[12] = a0 * wr3.x; po[13] = a0 * wr3.y; po[14] = a0 * wr3.z; po[15] = a0 * wr3.w;
        float vr[3] = {a1, a2, a3};
        #pragma unroll
        for (int r = 1; r < 4; ++r) {
            float4 u0 = *(const float4*)&W2[(size_t)(f0 + r) * 16];
            float4 u1 = *(const float4*)&W2[(size_t)(f0 + r) * 16 + 4];
            float4 u2 = *(const float4*)&W2[(size_t)(f0 + r) * 16 + 8];
            float4 u3 = *(const float4*)&W2[(size_t)(f0 + r) * 16 + 12];
            float v = vr[r - 1];
            po[0] += v * u0.x; po[1] += v * u0.y; po[2] += v * u0.z; po[3] += v * u0.w;
            po[4] += v * u1.x; po[5] += v * u1.y; po[6] += v * u1.z; po[7] += v * u1.w;
            po[8] += v * u2.x; po[9] += v * u2.y; po[10] += v * u2.z; po[11] += v * u2.w;
            po[12] += v * u3.x; po[13] += v * u3.y; po[14] += v * u3.z; po[15] += v * u3.w;
        }
    }
    #pragma unroll
    for (int o = 0; o < 16; ++o) pored[t][o] = po[o];
    __syncthreads();
    if (t < 16) {
        float s = 0.f;
        #pragma unroll 8
        for (int k = 0; k < 64; ++k) s += pored[k][t];
        h2part[(size_t)(q * 4096 + i) * 16 + t] = s;
    }
}

// ---------- K4: h2 = sum_q h2part; f_src2/f_dst2 ----------
__global__ __launch_bounds__(256) void coef2(const float* __restrict__ h2part,
                                             const float* __restrict__ a_src2,
                                             const float* __restrict__ a_dst2,
                                             float* __restrict__ h2,
                                             float* __restrict__ f_src2,
                                             float* __restrict__ f_dst2) {
    int idx = blockIdx.x * 256 + threadIdx.x;   // i*16+o
    int i = idx >> 4, o = idx & 15;
    float s = h2part[idx] + h2part[65536 + idx] + h2part[131072 + idx] + h2part[196608 + idx];
    h2[idx] = s;
    float ps = s * a_src2[o];
    float pd = s * a_dst2[o];
    #pragma unroll
    for (int off = 1; off < 16; off <<= 1) {
        ps += __shfl_xor(ps, off);
        pd += __shfl_xor(pd, off);
    }
    if (o == 0) { f_src2[i] = ps; f_dst2[i] = pd; }
}

// ---------- K5: layer-2 aggregation + elu + log_softmax ----------
__global__ __launch_bounds__(64) void final_layer(const float* __restrict__ h2,
                                                  const int* __restrict__ nbr_idx,
                                                  const int* __restrict__ nbr_cnt,
                                                  const float* __restrict__ f_src2,
                                                  const float* __restrict__ f_dst2,
                                                  float* __restrict__ out) {
    __shared__ float attn[MAXNBR];
    __shared__ int nbr[MAXNBR];
    int i = blockIdx.x;
    int l = threadIdx.x;
    int cnt = nbr_cnt[i];
    float fsi = f_src2[i];
    for (int j = l; j < MAXNBR; j += 64) {
        float e = -INFINITY;
        if (j < cnt) {
            int jj = nbr_idx[i * MAXNBR + j];
            nbr[j] = jj;
            float xv = fsi + f_dst2[jj];
            e = xv > 0.f ? xv : ALPHA * xv;
        }
        attn[j] = e;
    }
    __syncthreads();
    float m = fmaxf(attn[l], attn[l + 64]);
    #pragma unroll
    for (int off = 1; off < 64; off <<= 1) m = fmaxf(m, __shfl_xor(m, off));
    float s = 0.f;
    {
        float e0 = attn[l], e1 = attn[l + 64];
        if (e0 != -INFINITY) s += __expf(e0 - m);
        if (e1 != -INFINITY) s += __expf(e1 - m);
    }
    #pragma unroll
    for (int off = 1; off < 64; off <<= 1) s += __shfl_xor(s, off);
    for (int j = l; j < MAXNBR; j += 64) {
        float e = attn[j];
        attn[j] = (e == -INFINITY) ? 0.f : __expf(e - m) / s;
    }
    __syncthreads();
    if (l < 16) {
        float acc = 0.f;
        for (int j = 0; j < cnt; ++j)
            acc += attn[j] * h2[nbr[j] * 16 + l];
        float v = acc > 0.f ? acc : expm1f(acc);
        float mx = v;
        #pragma unroll
        for (int off = 1; off < 16; off <<= 1) mx = fmaxf(mx, __shfl_xor(mx, off));
        float se = __expf(v - mx);
        #pragma unroll
        for (int off = 1; off < 16; off <<= 1) se += __shfl_xor(se, off);
        out[i * 16 + l] = v - mx - logf(se);
    }
}

extern "C" void kernel_launch(void* const* d_in, const int* in_sizes, int n_in,
                              void* d_out, int out_size, void* d_ws, size_t ws_size,
                              hipStream_t stream) {
    const float* x      = (const float*)d_in[0];
    const float* adj    = (const float*)d_in[1];
    const float* W1     = (const float*)d_in[2];
    const float* a_src1 = (const float*)d_in[3];
    const float* a_dst1 = (const float*)d_in[4];
    const float* W2     = (const float*)d_in[5];
    const float* a_src2 = (const float*)d_in[6];
    const float* a_dst2 = (const float*)d_in[7];
    float* out = (float*)d_out;

    char* ws = (char*)d_ws;
    unsigned short* xb    = (unsigned short*)ws;                      // 4 MB
    unsigned short* w1t   = (unsigned short*)(ws + (4u << 20));       // 1 MB
    unsigned short* h1b   = (unsigned short*)(ws + (6u << 20));       // 8 MB
    float* fsrc1 = (float*)(ws + (14u << 20));                        // 128 KB
    float* fdst1 = (float*)(ws + (14u << 20) + (128u << 10));         // 128 KB
    float* h2    = (float*)(ws + (15u << 20));                        // 256 KB
    float* fsrc2 = (float*)(ws + (15u << 20) + (256u << 10));         // 16 KB
    float* fdst2 = (float*)(ws + (15u << 20) + (272u << 10));         // 16 KB
    int* nbr_idx = (int*)(ws + (16u << 20));                          // 2 MB
    int* nbr_cnt = (int*)(ws + (18u << 20));                          // 16 KB
    float* h2part = (float*)(ws + (19u << 20));                       // 1 MB

    cvt<<<3072, 256, 0, stream>>>(x, xb, W1, w1t);
    gemm_scan<<<1536, 256, 0, stream>>>(xb, w1t, h1b, adj, nbr_idx, nbr_cnt);
    attn_coef1<<<4096, 256, 0, stream>>>(h1b, a_src1, a_dst1, fsrc1, fdst1);
    aggregate2<<<16384, 64, 0, stream>>>(h1b, nbr_idx, nbr_cnt, fsrc1, fdst1, W2, h2part);
    coef2<<<256, 256, 0, stream>>>(h2part, a_src2, a_dst2, h2, fsrc2, fdst2);
    final_layer<<<4096, 64, 0, stream>>>(h2, nbr_idx, nbr_cnt, fsrc2, fdst2, out);
}

// Round 6
// 72.323 us; speedup vs baseline: 1.2274x; 1.2274x over previous
//
#include <hip/hip_runtime.h>
#include <hip/hip_bf16.h>
#include <hip/hip_fp16.h>

typedef __attribute__((ext_vector_type(8))) short short8;
typedef __attribute__((ext_vector_type(8))) _Float16 half8;
typedef __attribute__((ext_vector_type(4))) float f32x4;

#define MAXNBR 128
#define ALPHA 0.2f

static __device__ __forceinline__ unsigned short f2h(float f) {
    return __half_as_ushort(__float2half(f));
}
static __device__ __forceinline__ float h2f(unsigned short u) {
    return __half2float(__ushort_as_half(u));
}

// ---------- K0: cvt x -> f16, W1 -> W1t f16 ----------
__global__ __launch_bounds__(256) void cvt(const float* __restrict__ x,
                                           unsigned short* __restrict__ xh,
                                           const float* __restrict__ W1,
                                           unsigned short* __restrict__ W1t) {
    int b = blockIdx.x, t = threadIdx.x;
    if (b < 1024) {                       // x: 8 elems/thread
        size_t base = (size_t)b * 2048 + t * 8;
        float4 v0 = *(const float4*)&x[base];
        float4 v1 = *(const float4*)&x[base + 4];
        short8 o;
        o[0] = f2h(v0.x); o[1] = f2h(v0.y); o[2] = f2h(v0.z); o[3] = f2h(v0.w);
        o[4] = f2h(v1.x); o[5] = f2h(v1.y); o[6] = f2h(v1.z); o[7] = f2h(v1.w);
        *(short8*)&xh[base] = o;
    } else {                              // W1t transpose: 1 elem/thread
        int idx = (b - 1024) * 256 + t;   // out index c*512+k
        int c = idx >> 9, k = idx & 511;
        W1t[idx] = f2h(W1[(size_t)k * 1024 + c]);
    }
}

// ---------- K1: fused GEMM (512 blocks) + adjacency scan (1024 blocks) ----------
__global__ __launch_bounds__(256) void gemm_scan(const unsigned short* __restrict__ A,
                                                 const unsigned short* __restrict__ Bt,
                                                 unsigned short* __restrict__ C,
                                                 const float* __restrict__ adj,
                                                 int* __restrict__ nbr_idx,
                                                 int* __restrict__ nbr_cnt) {
    __shared__ unsigned short Asm[128 * 64];   // 16 KB
    __shared__ unsigned short Bsm[64 * 64];    //  8 KB
    int b = blockIdx.x;
    int tid = threadIdx.x;
    if (b < 512) {
        // ----- GEMM: h1h[4096][1024] = xh[4096][512] @ W1t; BM=128 BN=64 -----
        int lane = tid & 63;
        int w = tid >> 6;
        int wr = w >> 1, wc = w & 1;           // waves 2x2; wave tile 64x32
        int rowBase = (b & 31) * 128, colBase = (b >> 5) * 64;
        int lr = lane >> 3;
        int lc = (lane & 7) * 8;
        f32x4 acc[4][2] = {};
        for (int k0 = 0; k0 < 512; k0 += 64) {
            #pragma unroll
            for (int i = 0; i < 4; ++i) {
                int rA = i * 32 + w * 8;
                __builtin_amdgcn_global_load_lds(
                    (const __attribute__((address_space(1))) void*)&A[(size_t)(rowBase + rA + lr) * 512 + k0 + lc],
                    (__attribute__((address_space(3))) void*)&Asm[rA * 64],
                    16, 0, 0);
            }
            #pragma unroll
            for (int i = 0; i < 2; ++i) {
                int rB = i * 32 + w * 8;
                __builtin_amdgcn_global_load_lds(
                    (const __attribute__((address_space(1))) void*)&Bt[(size_t)(colBase + rB + lr) * 512 + k0 + lc],
                    (__attribute__((address_space(3))) void*)&Bsm[rB * 64],
                    16, 0, 0);
            }
            __syncthreads();
            #pragma unroll
            for (int kk = 0; kk < 64; kk += 32) {
                half8 af[4], bfv[2];
                int kf = kk + (lane >> 4) * 8;
                #pragma unroll
                for (int m = 0; m < 4; ++m)
                    af[m] = *(const half8*)&Asm[(wr * 64 + m * 16 + (lane & 15)) * 64 + kf];
                #pragma unroll
                for (int n = 0; n < 2; ++n)
                    bfv[n] = *(const half8*)&Bsm[(wc * 32 + n * 16 + (lane & 15)) * 64 + kf];
                #pragma unroll
                for (int m = 0; m < 4; ++m)
                    #pragma unroll
                    for (int n = 0; n < 2; ++n)
                        acc[m][n] = __builtin_amdgcn_mfma_f32_16x16x32_f16(af[m], bfv[n], acc[m][n], 0, 0, 0);
            }
            __syncthreads();
        }
        int crow0 = rowBase + wr * 64, ccol0 = colBase + wc * 32;
        #pragma unroll
        for (int m = 0; m < 4; ++m)
            #pragma unroll
            for (int n = 0; n < 2; ++n) {
                int col = ccol0 + n * 16 + (lane & 15);
                int row0 = crow0 + m * 16 + (lane >> 4) * 4;
                #pragma unroll
                for (int r = 0; r < 4; ++r)
                    C[(size_t)(row0 + r) * 1024 + col] = f2h(acc[m][n][r]);
            }
    } else {
        // ----- adjacency scan: 4 rows/block, one wave each -----
        int row = (b - 512) * 4 + (tid >> 6);
        int lane = tid & 63;
        const float* arow = adj + (size_t)row * 4096;
        int cnt = 0;
        for (int base = 0; base < 4096; base += 256) {
            float4 v = *(const float4*)&arow[base + lane * 4];
            #pragma unroll
            for (int s = 0; s < 4; ++s) {
                float xv = ((const float*)&v)[s];
                unsigned long long m = __ballot(xv > 0.f);
                if (xv > 0.f) {
                    int pos = cnt + (int)__popcll(m & ((1ull << lane) - 1ull));
                    if (pos < MAXNBR) nbr_idx[row * MAXNBR + pos] = base + lane * 4 + s;
                }
                cnt += (int)__popcll(m);
            }
        }
        if (lane == 0) nbr_cnt[row] = cnt < MAXNBR ? cnt : MAXNBR;
    }
}

// ---------- K2: f_src1/f_dst1 [8][4096] from f16 h1 ----------
__global__ __launch_bounds__(256) void attn_coef1(const unsigned short* __restrict__ h1h,
                                                  const float* __restrict__ a_src,
                                                  const float* __restrict__ a_dst,
                                                  float* __restrict__ f_src,
                                                  float* __restrict__ f_dst) {
    int n = blockIdx.x, t = threadIdx.x;
    ushort4 v = *(const ushort4*)&h1h[(size_t)n * 1024 + t * 4];
    int head = t >> 5;
    int o0 = (t * 4) & 127;
    float hv0 = h2f(v.x), hv1 = h2f(v.y), hv2 = h2f(v.z), hv3 = h2f(v.w);
    float ps = hv0 * a_src[head * 128 + o0] + hv1 * a_src[head * 128 + o0 + 1]
             + hv2 * a_src[head * 128 + o0 + 2] + hv3 * a_src[head * 128 + o0 + 3];
    float pd = hv0 * a_dst[head * 128 + o0] + hv1 * a_dst[head * 128 + o0 + 1]
             + hv2 * a_dst[head * 128 + o0 + 2] + hv3 * a_dst[head * 128 + o0 + 3];
    #pragma unroll
    for (int off = 1; off < 32; off <<= 1) {
        ps += __shfl_xor(ps, off);
        pd += __shfl_xor(pd, off);
    }
    if ((t & 31) == 0) {
        f_src[head * 4096 + n] = ps;
        f_dst[head * 4096 + n] = pd;
    }
}

// ---------- K3: XCD-affine aggregate: block = 4 nodes x 1 quarter, 1 wave/node ----------
// bid = grp*4 + q -> XCD = bid%8 = q + 4*(grp&1): each XCD touches only a 2 MB
// column stripe of h1h (L2-resident). 4-wave blocks -> up to 32 waves/CU.
__global__ __launch_bounds__(256) void aggregate3(const unsigned short* __restrict__ h1h,
                                                  const int* __restrict__ nbr_idx,
                                                  const int* __restrict__ nbr_cnt,
                                                  const float* __restrict__ f_src,
                                                  const float* __restrict__ f_dst,
                                                  unsigned short* __restrict__ h1act) {
    __shared__ int nbrS[4][MAXNBR];      // 2 KB
    __shared__ float attwS[4][2][MAXNBR];// 4 KB
    int bid = blockIdx.x;
    int q = bid & 3;
    int grp = bid >> 2;
    int w = threadIdx.x >> 6;            // wave = node within group
    int t = threadIdx.x & 63;            // lane
    int i = grp * 4 + w;
    int cnt = nbr_cnt[i];
    int* nbr = nbrS[w];
    nbr[t]      = (t < cnt)      ? nbr_idx[i * MAXNBR + t]      : 0;
    nbr[t + 64] = (t + 64 < cnt) ? nbr_idx[i * MAXNBR + t + 64] : 0;
    __syncthreads();
    int hl = t >> 5;                     // local head 0/1
    int h = q * 2 + hl;                  // global head
    // ---- softmax (lanes 0-31: head 2q, lanes 32-63: head 2q+1) ----
    {
        int sl = t & 31;
        float fsh = f_src[h * 4096 + i];
        float e[4];
        #pragma unroll
        for (int p = 0; p < 4; ++p) {
            int j = sl + p * 32;
            if (j < cnt) {
                float xv = fsh + f_dst[h * 4096 + nbr[j]];
                e[p] = xv > 0.f ? xv : ALPHA * xv;
            } else e[p] = -INFINITY;
        }
        float m = fmaxf(fmaxf(e[0], e[1]), fmaxf(e[2], e[3]));
        #pragma unroll
        for (int off = 1; off < 32; off <<= 1) m = fmaxf(m, __shfl_xor(m, off));
        float wq[4];
        float s = 0.f;
        #pragma unroll
        for (int p = 0; p < 4; ++p) {
            wq[p] = (e[p] == -INFINITY) ? 0.f : __expf(e[p] - m);
            s += wq[p];
        }
        #pragma unroll
        for (int off = 1; off < 32; off <<= 1) s += __shfl_xor(s, off);
        float inv = 1.f / s;
        #pragma unroll
        for (int p = 0; p < 4; ++p) attwS[w][hl][sl + p * 32] = wq[p] * inv;
    }
    __syncthreads();
    // ---- gather: lane t owns feats q*256 + t*4 .. +3 (head hl of quarter) ----
    const float* attw = attwS[w][hl];
    const unsigned short* src = h1h + q * 256 + t * 4;
    float a0 = 0.f, a1 = 0.f, a2 = 0.f, a3 = 0.f;
    int cntPad = (cnt + 7) & ~7;
    for (int j = 0; j < cntPad; j += 8) {
        int4 nb0 = *(const int4*)&nbr[j];
        int4 nb1 = *(const int4*)&nbr[j + 4];
        float4 w0 = *(const float4*)&attw[j];
        float4 w1 = *(const float4*)&attw[j + 4];
        ushort4 v0 = *(const ushort4*)&src[(size_t)nb0.x << 10];
        ushort4 v1 = *(const ushort4*)&src[(size_t)nb0.y << 10];
        ushort4 v2 = *(const ushort4*)&src[(size_t)nb0.z << 10];
        ushort4 v3 = *(const ushort4*)&src[(size_t)nb0.w << 10];
        ushort4 v4 = *(const ushort4*)&src[(size_t)nb1.x << 10];
        ushort4 v5 = *(const ushort4*)&src[(size_t)nb1.y << 10];
        ushort4 v6 = *(const ushort4*)&src[(size_t)nb1.z << 10];
        ushort4 v7 = *(const ushort4*)&src[(size_t)nb1.w << 10];
        a0 += w0.x * h2f(v0.x) + w0.y * h2f(v1.x) + w0.z * h2f(v2.x) + w0.w * h2f(v3.x)
            + w1.x * h2f(v4.x) + w1.y * h2f(v5.x) + w1.z * h2f(v6.x) + w1.w * h2f(v7.x);
        a1 += w0.x * h2f(v0.y) + w0.y * h2f(v1.y) + w0.z * h2f(v2.y) + w0.w * h2f(v3.y)
            + w1.x * h2f(v4.y) + w1.y * h2f(v5.y) + w1.z * h2f(v6.y) + w1.w * h2f(v7.y);
        a2 += w0.x * h2f(v0.z) + w0.y * h2f(v1.z) + w0.z * h2f(v2.z) + w0.w * h2f(v3.z)
            + w1.x * h2f(v4.z) + w1.y * h2f(v5.z) + w1.z * h2f(v6.z) + w1.w * h2f(v7.z);
        a3 += w0.x * h2f(v0.w) + w0.y * h2f(v1.w) + w0.z * h2f(v2.w) + w0.w * h2f(v3.w)
            + w1.x * h2f(v4.w) + w1.y * h2f(v5.w) + w1.z * h2f(v6.w) + w1.w * h2f(v7.w);
    }
    a0 = a0 > 0.f ? a0 : expm1f(a0);
    a1 = a1 > 0.f ? a1 : expm1f(a1);
    a2 = a2 > 0.f ? a2 : expm1f(a2);
    a3 = a3 > 0.f ? a3 : expm1f(a3);
    ushort4 o;
    o.x = f2h(a0); o.y = f2h(a1); o.z = f2h(a2); o.w = f2h(a3);
    *(ushort4*)&h1act[(size_t)i * 1024 + q * 256 + t * 4] = o;
}

// ---------- K4: h2 = h1act @ W2 [1024][16] + f_src2/f_dst2 ----------
__global__ __launch_bounds__(256) void layer2_gemm(const unsigned short* __restrict__ h1act,
                                                   const float* __restrict__ W2,
                                                   const float* __restrict__ a_src2,
                                                   const float* __restrict__ a_dst2,
                                                   float* __restrict__ h2,
                                                   float* __restrict__ f_src2,
                                                   float* __restrict__ f_dst2) {
    __shared__ float row[1024];
    __shared__ float partial[16][17];
    __shared__ float h2row[16];
    int n = blockIdx.x, t = threadIdx.x;
    {
        ushort4 v = *(const ushort4*)&h1act[(size_t)n * 1024 + t * 4];
        row[t * 4]     = h2f(v.x);
        row[t * 4 + 1] = h2f(v.y);
        row[t * 4 + 2] = h2f(v.z);
        row[t * 4 + 3] = h2f(v.w);
    }
    __syncthreads();
    int o = t & 15, seg = t >> 4;
    float acc = 0.f;
    #pragma unroll 8
    for (int k = seg * 64; k < seg * 64 + 64; ++k)
        acc += row[k] * W2[k * 16 + o];
    partial[seg][o] = acc;
    __syncthreads();
    if (t < 16) {
        float s = 0.f;
        #pragma unroll
        for (int g = 0; g < 16; ++g) s += partial[g][t];
        h2[n * 16 + t] = s;
        h2row[t] = s;
    }
    __syncthreads();
    if (t < 16) {
        float ps = h2row[t] * a_src2[t];
        float pd = h2row[t] * a_dst2[t];
        #pragma unroll
        for (int off = 1; off < 16; off <<= 1) {
            ps += __shfl_xor(ps, off);
            pd += __shfl_xor(pd, off);
        }
        if (t == 0) { f_src2[n] = ps; f_dst2[n] = pd; }
    }
}

// ---------- K5: layer-2 aggregation + elu + log_softmax ----------
__global__ __launch_bounds__(64) void final_layer(const float* __restrict__ h2,
                                                  const int* __restrict__ nbr_idx,
                                                  const int* __restrict__ nbr_cnt,
                                                  const float* __restrict__ f_src2,
                                                  const float* __restrict__ f_dst2,
                                                  float* __restrict__ out) {
    __shared__ float attn[MAXNBR];
    __shared__ int nbr[MAXNBR];
    int i = blockIdx.x;
    int l = threadIdx.x;
    int cnt = nbr_cnt[i];
    float fsi = f_src2[i];
    for (int j = l; j < MAXNBR; j += 64) {
        float e = -INFINITY;
        if (j < cnt) {
            int jj = nbr_idx[i * MAXNBR + j];
            nbr[j] = jj;
            float xv = fsi + f_dst2[jj];
            e = xv > 0.f ? xv : ALPHA * xv;
        }
        attn[j] = e;
    }
    __syncthreads();
    float m = fmaxf(attn[l], attn[l + 64]);
    #pragma unroll
    for (int off = 1; off < 64; off <<= 1) m = fmaxf(m, __shfl_xor(m, off));
    float s = 0.f;
    {
        float e0 = attn[l], e1 = attn[l + 64];
        if (e0 != -INFINITY) s += __expf(e0 - m);
        if (e1 != -INFINITY) s += __expf(e1 - m);
    }
    #pragma unroll
    for (int off = 1; off < 64; off <<= 1) s += __shfl_xor(s, off);
    for (int j = l; j < MAXNBR; j += 64) {
        float e = attn[j];
        attn[j] = (e == -INFINITY) ? 0.f : __expf(e - m) / s;
    }
    __syncthreads();
    if (l < 16) {
        float acc = 0.f;
        for (int j = 0; j < cnt; ++j)
            acc += attn[j] * h2[nbr[j] * 16 + l];
        float v = acc > 0.f ? acc : expm1f(acc);
        float mx = v;
        #pragma unroll
        for (int off = 1; off < 16; off <<= 1) mx = fmaxf(mx, __shfl_xor(mx, off));
        float se = __expf(v - mx);
        #pragma unroll
        for (int off = 1; off < 16; off <<= 1) se += __shfl_xor(se, off);
        out[i * 16 + l] = v - mx - logf(se);
    }
}

extern "C" void kernel_launch(void* const* d_in, const int* in_sizes, int n_in,
                              void* d_out, int out_size, void* d_ws, size_t ws_size,
                              hipStream_t stream) {
    const float* x      = (const float*)d_in[0];
    const float* adj    = (const float*)d_in[1];
    const float* W1     = (const float*)d_in[2];
    const float* a_src1 = (const float*)d_in[3];
    const float* a_dst1 = (const float*)d_in[4];
    const float* W2     = (const float*)d_in[5];
    const float* a_src2 = (const float*)d_in[6];
    const float* a_dst2 = (const float*)d_in[7];
    float* out = (float*)d_out;

    char* ws = (char*)d_ws;
    unsigned short* xh    = (unsigned short*)ws;                      // 4 MB
    unsigned short* w1t   = (unsigned short*)(ws + (4u << 20));       // 1 MB
    unsigned short* h1h   = (unsigned short*)(ws + (6u << 20));       // 8 MB
    unsigned short* h1act = (unsigned short*)(ws + (26u << 20));      // 8 MB
    float* fsrc1 = (float*)(ws + (14u << 20));                        // 128 KB
    float* fdst1 = (float*)(ws + (14u << 20) + (128u << 10));         // 128 KB
    float* h2    = (float*)(ws + (15u << 20));                        // 256 KB
    float* fsrc2 = (float*)(ws + (15u << 20) + (256u << 10));         // 16 KB
    float* fdst2 = (float*)(ws + (15u << 20) + (272u << 10));         // 16 KB
    int* nbr_idx = (int*)(ws + (16u << 20));                          // 2 MB
    int* nbr_cnt = (int*)(ws + (18u << 20));                          // 16 KB

    cvt<<<3072, 256, 0, stream>>>(x, xh, W1, w1t);
    gemm_scan<<<1536, 256, 0, stream>>>(xh, w1t, h1h, adj, nbr_idx, nbr_cnt);
    attn_coef1<<<4096, 256, 0, stream>>>(h1h, a_src1, a_dst1, fsrc1, fdst1);
    aggregate3<<<4096, 256, 0, stream>>>(h1h, nbr_idx, nbr_cnt, fsrc1, fdst1, h1act);
    layer2_gemm<<<4096, 256, 0, stream>>>(h1act, W2, a_src2, a_dst2, h2, fsrc2, fdst2);
    final_layer<<<4096, 64, 0, stream>>>(h2, nbr_idx, nbr_cnt, fsrc2, fdst2, out);
}